// Round 5
// baseline (495.878 us; speedup 1.0000x reference)
//
#include <hip/hip_runtime.h>

#define IN_DIM 64
#define HID 32
#define SHIFT 8
#define BKEYS 256            // node keys per bucket
#define CAP 4608             // bucket capacity (mean 4096, sigma~64 -> +8 sigma)
#define CHUNK 2048           // edges per multisplit block
#define MAXB 512             // max buckets (N <= 131072)

// ---- K1: multisplit edges into buckets (by dst for aggregation, by src for deg_out) ----
__global__ __launch_bounds__(512) void multisplit_kernel(
    const int* __restrict__ src, const int* __restrict__ dst, int E, int NB,
    unsigned* __restrict__ gcur_d, unsigned* __restrict__ gcur_s,
    unsigned* __restrict__ bkt_pairs, unsigned* __restrict__ bkt_srcs)
{
    __shared__ unsigned hist_d[MAXB], base_d[MAXB], cur_d[MAXB], gb_d[MAXB];
    __shared__ unsigned hist_s[MAXB], base_s[MAXB], cur_s[MAXB], gb_s[MAXB];
    __shared__ uint2    stg_p[CHUNK];          // (src, dst), 16 KB
    __shared__ unsigned stg_s[CHUNK];          // src stream, 8 KB
    int t = threadIdx.x;
    int e0 = blockIdx.x * CHUNK;
    int cnt = min(CHUNK, E - e0);

    hist_d[t] = 0; hist_s[t] = 0; cur_d[t] = 0; cur_s[t] = 0;   // t < 512 == MAXB
    __syncthreads();
    for (int i = t; i < cnt; i += 512) {
        int d = dst[e0 + i], s = src[e0 + i];
        atomicAdd(&hist_d[d >> SHIFT], 1u);
        atomicAdd(&hist_s[s >> SHIFT], 1u);
    }
    __syncthreads();
    unsigned hd = hist_d[t], hs = hist_s[t];
    base_d[t] = hd; base_s[t] = hs;
    __syncthreads();
    for (int off = 1; off < MAXB; off <<= 1) {
        unsigned vd = (t >= off) ? base_d[t - off] : 0;
        unsigned vs = (t >= off) ? base_s[t - off] : 0;
        __syncthreads();
        base_d[t] += vd; base_s[t] += vs;
        __syncthreads();
    }
    if (t < NB) {
        base_d[t] -= hd; base_s[t] -= hs;        // exclusive
        gb_d[t] = atomicAdd(&gcur_d[t], hd);
        gb_s[t] = atomicAdd(&gcur_s[t], hs);
    }
    __syncthreads();
    for (int i = t; i < cnt; i += 512) {
        int d = dst[e0 + i], s = src[e0 + i];
        int kd = d >> SHIFT, ks = s >> SHIFT;
        unsigned r = atomicAdd(&cur_d[kd], 1u);
        stg_p[base_d[kd] + r] = make_uint2((unsigned)s, (unsigned)d);
        unsigned r2 = atomicAdd(&cur_s[ks], 1u);
        stg_s[base_s[ks] + r2] = (unsigned)s;
    }
    __syncthreads();
    for (int i = t; i < cnt; i += 512) {
        uint2 p = stg_p[i];
        int bin = p.y >> SHIFT;
        unsigned pos = gb_d[bin] + ((unsigned)i - base_d[bin]);
        if (pos < CAP)
            bkt_pairs[(size_t)bin * CAP + pos] = ((p.y & (BKEYS - 1)) << 17) | p.x;
        unsigned s = stg_s[i];
        int bs = s >> SHIFT;
        unsigned pos2 = gb_s[bs] + ((unsigned)i - base_s[bs]);
        if (pos2 < CAP)
            bkt_srcs[(size_t)bs * CAP + pos2] = s;
    }
}

// ---- K2: per-bucket out-degree -> norm_src (LDS atomics only) ----
__global__ __launch_bounds__(512) void degnorm_kernel(
    const unsigned* __restrict__ bkt_srcs, const unsigned* __restrict__ gcur_s,
    int N, float* __restrict__ norm_src)
{
    __shared__ unsigned cnt[BKEYS];
    int t = threadIdx.x;
    int bin = blockIdx.x;
    if (t < BKEYS) cnt[t] = 0;
    __syncthreads();
    unsigned m = gcur_s[bin];
    if (m > CAP) m = CAP;
    const unsigned* bs = bkt_srcs + (size_t)bin * CAP;
    for (unsigned i = t; i < m; i += 512) atomicAdd(&cnt[bs[i] & (BKEYS - 1)], 1u);
    __syncthreads();
    if (t < BKEYS) {
        int v = bin * BKEYS + t;
        if (v < N) norm_src[v] = rsqrtf(fmaxf((float)cnt[t], 1.0f));
    }
}

// ---- K3: h = (X @ W) * norm_src, 128 nodes/block ----
__global__ void xw_kernel(const float* __restrict__ X, const float* __restrict__ W,
                          const float* __restrict__ norm_src, float* __restrict__ h, int N) {
    __shared__ float Ws[IN_DIM * HID];
    __shared__ float Xs[8][IN_DIM];
    int t = threadIdx.x;
    if (t < 128) {
        ((float4*)Ws)[t]       = ((const float4*)W)[t];
        ((float4*)Ws)[t + 128] = ((const float4*)W)[t + 128];
        ((float4*)Ws)[t + 256] = ((const float4*)W)[t + 256];
        ((float4*)Ws)[t + 384] = ((const float4*)W)[t + 384];
    }
    int ln = t >> 5, d = t & 31;
    for (int rep = 0; rep < 16; ++rep) {
        int node0 = blockIdx.x * 128 + rep * 8;
        __syncthreads();
        if (t < 128) {
            int n = node0 + (t >> 4);
            if (n < N) ((float4*)Xs)[t] = ((const float4*)X)[(size_t)n * 16 + (t & 15)];
            else ((float4*)Xs)[t] = make_float4(0.f, 0.f, 0.f, 0.f);
        }
        __syncthreads();
        int node = node0 + ln;
        if (node < N) {
            float acc = 0.0f;
#pragma unroll
            for (int k = 0; k < IN_DIM; ++k) acc += Xs[ln][k] * Ws[k * HID + d];
            h[(size_t)node * HID + d] = acc * norm_src[node];
        }
    }
}

// ---- K4: fused aggregation: per-bucket LDS accumulator, epilogue fused ----
// 32 lanes per edge (1 dword each); LDS row rotate-swizzle (d+ld)&31 gives
// exactly 2 lanes/bank per ds_add instruction (free per m136).
__global__ __launch_bounds__(512) void agg_kernel(
    const unsigned* __restrict__ bkt_pairs, const unsigned* __restrict__ gcur_d,
    const float* __restrict__ h, const float* __restrict__ bias,
    float* __restrict__ out, int N)
{
    __shared__ float acc[BKEYS * HID];   // 32 KB
    __shared__ unsigned dcnt[BKEYS];
    int t = threadIdx.x;
    int bin = blockIdx.x;
    for (int i = t; i < BKEYS * HID; i += 512) acc[i] = 0.f;
    if (t < BKEYS) dcnt[t] = 0;
    __syncthreads();
    unsigned m = gcur_d[bin];
    if (m > CAP) m = CAP;
    const unsigned* bp = bkt_pairs + (size_t)bin * CAP;
    int d = t & 31;            // dim within row
    unsigned slot = t >> 5;    // edge slot 0..15
    unsigned i = slot;
    for (; i + 48 < m; i += 64) {         // 4 edges in flight per half-wave
        unsigned p0 = bp[i], p1 = bp[i + 16], p2 = bp[i + 32], p3 = bp[i + 48];
        float h0 = h[(size_t)(p0 & 0x1FFFFu) * HID + d];
        float h1 = h[(size_t)(p1 & 0x1FFFFu) * HID + d];
        float h2 = h[(size_t)(p2 & 0x1FFFFu) * HID + d];
        float h3 = h[(size_t)(p3 & 0x1FFFFu) * HID + d];
        unsigned l0 = p0 >> 17, l1 = p1 >> 17, l2 = p2 >> 17, l3 = p3 >> 17;
        atomicAdd(&acc[l0 * HID + ((d + l0) & 31)], h0);
        atomicAdd(&acc[l1 * HID + ((d + l1) & 31)], h1);
        atomicAdd(&acc[l2 * HID + ((d + l2) & 31)], h2);
        atomicAdd(&acc[l3 * HID + ((d + l3) & 31)], h3);
        if (d == 0) {
            atomicAdd(&dcnt[l0], 1u); atomicAdd(&dcnt[l1], 1u);
            atomicAdd(&dcnt[l2], 1u); atomicAdd(&dcnt[l3], 1u);
        }
    }
    for (; i < m; i += 16) {
        unsigned p = bp[i];
        unsigned l = p >> 17;
        atomicAdd(&acc[l * HID + ((d + l) & 31)], h[(size_t)(p & 0x1FFFFu) * HID + d]);
        if (d == 0) atomicAdd(&dcnt[l], 1u);
    }
    __syncthreads();
    // epilogue: norm_dst + bias + relu, coalesced store
    for (int k = t; k < BKEYS * HID; k += 512) {
        int ld = k >> 5, dd = k & 31;
        int v = bin * BKEYS + ld;
        if (v < N) {
            float nv = rsqrtf(fmaxf((float)dcnt[ld], 1.0f));
            float o = acc[ld * HID + ((dd + ld) & 31)] * nv + bias[dd];
            out[(size_t)v * HID + dd] = fmaxf(o, 0.f);
        }
    }
}

extern "C" void kernel_launch(void* const* d_in, const int* in_sizes, int n_in,
                              void* d_out, int out_size, void* d_ws, size_t ws_size,
                              hipStream_t stream) {
    const float* X   = (const float*)d_in[0];
    const int*   src = (const int*)d_in[1];
    const int*   dst = (const int*)d_in[2];
    const float* W   = (const float*)d_in[3];
    const float* b   = (const float*)d_in[4];
    float* out = (float*)d_out;

    int N = in_sizes[0] / IN_DIM;       // 100000
    int E = in_sizes[1];                // 1600000
    int NB = (N + BKEYS - 1) / BKEYS;   // 391

    // ws layout (u32): [gcur_d 512][gcur_s 512][norm_src N][bkt_pairs NB*CAP]
    //                  [bkt_srcs NB*CAP ... h aliases bkt_srcs+tail (N*32)]
    // order: multisplit -> degnorm(reads srcs) -> xw(writes h over srcs) -> agg(reads pairs,h)
    unsigned* gcur_d = (unsigned*)d_ws;
    unsigned* gcur_s = gcur_d + 512;
    float* norm_src  = (float*)(gcur_s + 512);
    unsigned* bkt_pairs = (unsigned*)(norm_src + N);
    unsigned* bkt_srcs  = bkt_pairs + (size_t)NB * CAP;
    float* h = (float*)bkt_srcs;        // srcs dead after degnorm

    hipMemsetAsync(gcur_d, 0, 1024 * sizeof(unsigned), stream);

    multisplit_kernel<<<(E + CHUNK - 1) / CHUNK, 512, 0, stream>>>(
        src, dst, E, NB, gcur_d, gcur_s, bkt_pairs, bkt_srcs);
    degnorm_kernel<<<NB, 512, 0, stream>>>(bkt_srcs, gcur_s, N, norm_src);
    xw_kernel<<<(N + 127) / 128, 256, 0, stream>>>(X, W, norm_src, h, N);
    agg_kernel<<<NB, 512, 0, stream>>>(bkt_pairs, gcur_d, h, b, out, N);
}

// Round 6
// 177.751 us; speedup vs baseline: 2.7897x; 2.7897x over previous
//
#include <hip/hip_runtime.h>
#include <hip/hip_fp16.h>

#define IN_DIM 64
#define HID 32
#define SHIFT 8
#define BKEYS 256            // nodes per bin
#define CAP 4608             // bin capacity (mean 4096, sigma ~64 -> +8 sigma)
#define CHUNK 2048           // edges per multisplit block
#define MAXB 512             // max bins (N <= 131072)

// ---- K1: multisplit edges into bins (by dst for CSR+gather, by src for out-degree) ----
__global__ __launch_bounds__(256) void multisplit_kernel(
    const int* __restrict__ src, const int* __restrict__ dst, int E, int NB,
    unsigned* __restrict__ gcur_d, unsigned* __restrict__ gcur_s,
    unsigned* __restrict__ bkt_pairs, unsigned* __restrict__ bkt_srcs)
{
    __shared__ unsigned hist_d[MAXB], base_d[MAXB], cur_d[MAXB], gb_d[MAXB];
    __shared__ unsigned hist_s[MAXB], base_s[MAXB], cur_s[MAXB], gb_s[MAXB];
    __shared__ unsigned sc_d[256], sc_s[256];
    __shared__ unsigned stg_p[CHUNK];          // packed (localdst<<17)|src
    __shared__ unsigned short stg_bin[CHUNK];  // bin of each staged pair
    __shared__ unsigned stg_s[CHUNK];          // src stream
    int t = threadIdx.x;
    int e0 = blockIdx.x * CHUNK;
    int cnt = min(CHUNK, E - e0);

    // read this block's edges once into registers
    int ss[8], dd[8];
#pragma unroll
    for (int j = 0; j < 8; ++j) {
        int i = t + 256 * j;
        if (i < cnt) { ss[j] = src[e0 + i]; dd[j] = dst[e0 + i]; }
        else { ss[j] = -1; dd[j] = -1; }
    }
    for (int i = t; i < MAXB; i += 256) {
        hist_d[i] = 0; hist_s[i] = 0; cur_d[i] = 0; cur_s[i] = 0;
    }
    __syncthreads();
#pragma unroll
    for (int j = 0; j < 8; ++j) if (dd[j] >= 0) {
        atomicAdd(&hist_d[dd[j] >> SHIFT], 1u);
        atomicAdd(&hist_s[ss[j] >> SHIFT], 1u);
    }
    __syncthreads();
    // pair-scan: thread t owns bins 2t, 2t+1
    unsigned d0 = hist_d[2 * t], d1 = hist_d[2 * t + 1];
    unsigned s0 = hist_s[2 * t], s1 = hist_s[2 * t + 1];
    sc_d[t] = d0 + d1; sc_s[t] = s0 + s1;
    __syncthreads();
    for (int off = 1; off < 256; off <<= 1) {
        unsigned ud = (t >= off) ? sc_d[t - off] : 0;
        unsigned us = (t >= off) ? sc_s[t - off] : 0;
        __syncthreads();
        sc_d[t] += ud; sc_s[t] += us;
        __syncthreads();
    }
    unsigned ed = sc_d[t] - d0 - d1, es = sc_s[t] - s0 - s1;
    base_d[2 * t] = ed;      base_d[2 * t + 1] = ed + d0;
    base_s[2 * t] = es;      base_s[2 * t + 1] = es + s0;
    if (2 * t < NB)     { gb_d[2 * t]     = atomicAdd(&gcur_d[2 * t], d0);
                          gb_s[2 * t]     = atomicAdd(&gcur_s[2 * t], s0); }
    if (2 * t + 1 < NB) { gb_d[2 * t + 1] = atomicAdd(&gcur_d[2 * t + 1], d1);
                          gb_s[2 * t + 1] = atomicAdd(&gcur_s[2 * t + 1], s1); }
    __syncthreads();
    // rank & stage grouped-by-bin
#pragma unroll
    for (int j = 0; j < 8; ++j) if (dd[j] >= 0) {
        int kd = dd[j] >> SHIFT, ks = ss[j] >> SHIFT;
        unsigned r = atomicAdd(&cur_d[kd], 1u);
        unsigned pos = base_d[kd] + r;
        stg_p[pos] = (((unsigned)dd[j] & (BKEYS - 1)) << 17) | (unsigned)ss[j];
        stg_bin[pos] = (unsigned short)kd;
        unsigned r2 = atomicAdd(&cur_s[ks], 1u);
        stg_s[base_s[ks] + r2] = (unsigned)ss[j];
    }
    __syncthreads();
    // flush, coalesced within each bin run
    for (int i = t; i < cnt; i += 256) {
        unsigned p = stg_p[i];
        int bin = stg_bin[i];
        unsigned pos = gb_d[bin] + ((unsigned)i - base_d[bin]);
        if (pos < CAP) bkt_pairs[(size_t)bin * CAP + pos] = p;
        unsigned s = stg_s[i];
        int bs = s >> SHIFT;
        unsigned pos2 = gb_s[bs] + ((unsigned)i - base_s[bs]);
        if (pos2 < CAP) bkt_srcs[(size_t)bs * CAP + pos2] = s;
    }
}

// ---- K2: fused out-degree -> norm_src (LDS) -> h16 = fp16((X@W)*norm) for this bin ----
__global__ __launch_bounds__(512) void degxw_kernel(
    const unsigned* __restrict__ bkt_srcs, const unsigned* __restrict__ gcur_s,
    const float* __restrict__ X, const float* __restrict__ W,
    int N, unsigned short* __restrict__ h16)
{
    __shared__ float Ws[IN_DIM * HID];   // 8 KB
    __shared__ unsigned cnt[BKEYS];
    __shared__ float nrm[BKEYS];
    int t = threadIdx.x;
    int bin = blockIdx.x;
    ((float4*)Ws)[t] = ((const float4*)W)[t];      // 512 float4 by 512 threads
    if (t < BKEYS) cnt[t] = 0;
    __syncthreads();
    unsigned m = gcur_s[bin];
    if (m > CAP) m = CAP;
    const unsigned* bs = bkt_srcs + (size_t)bin * CAP;
    for (unsigned i = t; i < m; i += 512) atomicAdd(&cnt[bs[i] & (BKEYS - 1)], 1u);
    __syncthreads();
    if (t < BKEYS) nrm[t] = rsqrtf(fmaxf((float)cnt[t], 1.0f));
    __syncthreads();
    // h for the bin's 256 nodes: 8 threads/node (4 dims each), 64 nodes/pass
    int q = t & 7, ln8 = t >> 3;
#pragma unroll
    for (int pass = 0; pass < 4; ++pass) {
        int lv = pass * 64 + ln8;
        int v = bin * BKEYS + lv;
        if (v < N) {
            const float4* Xr = (const float4*)(X + (size_t)v * IN_DIM);
            float4 acc = make_float4(0.f, 0.f, 0.f, 0.f);
#pragma unroll
            for (int kk = 0; kk < 16; ++kk) {
                float4 xv = Xr[kk];
                int k0 = kk * 4;
                float4 w0 = ((float4*)Ws)[(k0 + 0) * 8 + q];
                float4 w1 = ((float4*)Ws)[(k0 + 1) * 8 + q];
                float4 w2 = ((float4*)Ws)[(k0 + 2) * 8 + q];
                float4 w3 = ((float4*)Ws)[(k0 + 3) * 8 + q];
                acc.x += xv.x * w0.x + xv.y * w1.x + xv.z * w2.x + xv.w * w3.x;
                acc.y += xv.x * w0.y + xv.y * w1.y + xv.z * w2.y + xv.w * w3.y;
                acc.z += xv.x * w0.z + xv.y * w1.z + xv.z * w2.z + xv.w * w3.z;
                acc.w += xv.x * w0.w + xv.y * w1.w + xv.z * w2.w + xv.w * w3.w;
            }
            float s = nrm[lv];
            __half2 a = __floats2half2_rn(acc.x * s, acc.y * s);
            __half2 b2 = __floats2half2_rn(acc.z * s, acc.w * s);
            uint2 u;
            u.x = *(unsigned*)&a;
            u.y = *(unsigned*)&b2;
            ((uint2*)h16)[(size_t)v * 8 + q] = u;   // row = 64 B = 8 uint2
        }
    }
}

// ---- K3: per-bin LDS CSR build + pull gather (fused epilogue), no global CSR ----
__global__ __launch_bounds__(512) void csrgather_kernel(
    const unsigned* __restrict__ bkt_pairs, const unsigned* __restrict__ gcur_d,
    const unsigned short* __restrict__ h16, const float* __restrict__ bias,
    float* __restrict__ out, int N)
{
    __shared__ unsigned cnt[BKEYS], ex[BKEYS], cur[BKEYS];
    __shared__ unsigned ecsr[CAP];    // 18 KB
    __shared__ float bsh[HID];
    int t = threadIdx.x;
    int bin = blockIdx.x;
    if (t < BKEYS) { cnt[t] = 0; cur[t] = 0; }
    if (t < HID) bsh[t] = bias[t];
    __syncthreads();
    unsigned m = gcur_d[bin];
    if (m > CAP) m = CAP;
    const unsigned* bp = bkt_pairs + (size_t)bin * CAP;
    for (unsigned i = t; i < m; i += 512) atomicAdd(&cnt[bp[i] >> 17], 1u);
    __syncthreads();
    unsigned c = (t < BKEYS) ? cnt[t] : 0;
    if (t < BKEYS) ex[t] = c;
    __syncthreads();
    for (int off = 1; off < BKEYS; off <<= 1) {
        unsigned u = (t >= off && t < BKEYS) ? ex[t - off] : 0;
        __syncthreads();
        if (t < BKEYS) ex[t] += u;          // inclusive
        __syncthreads();
    }
    for (unsigned i = t; i < m; i += 512) {
        unsigned p = bp[i];
        unsigned l = p >> 17;
        unsigned pos = (ex[l] - cnt[l]) + atomicAdd(&cur[l], 1u);
        ecsr[pos] = p & 0x1FFFFu;
    }
    __syncthreads();
    // gather: 8 waves x 32 nodes; 2 nodes per wave-iter; per node: 8 edge-slots x 4 lanes x 16B
    int lane = t & 63, w = t >> 6;
    int half = lane >> 5;           // node select within pair
    int slot = (lane >> 2) & 7;     // edge slot 0..7
    int q = lane & 3;               // dim octet 0..3 (8 fp16 dims)
    for (int j = 0; j < 16; ++j) {
        int lv = w * 32 + j * 2 + half;
        unsigned dg = cnt[lv];
        unsigned st = ex[lv] - dg;
        float a0=0.f,a1=0.f,a2=0.f,a3=0.f,a4=0.f,a5=0.f,a6=0.f,a7=0.f;
        for (unsigned u = st + slot; u < st + dg; u += 8) {
            unsigned s = ecsr[u];
            uint4 hv = ((const uint4*)h16)[(size_t)s * 4 + q];   // 16 B = 8 halves
            __half2* hp = (__half2*)&hv;
            float2 f0 = __half22float2(hp[0]);
            float2 f1 = __half22float2(hp[1]);
            float2 f2 = __half22float2(hp[2]);
            float2 f3 = __half22float2(hp[3]);
            a0 += f0.x; a1 += f0.y; a2 += f1.x; a3 += f1.y;
            a4 += f2.x; a5 += f2.y; a6 += f3.x; a7 += f3.y;
        }
#pragma unroll
        for (int off = 4; off <= 16; off <<= 1) {
            a0 += __shfl_xor(a0, off, 64); a1 += __shfl_xor(a1, off, 64);
            a2 += __shfl_xor(a2, off, 64); a3 += __shfl_xor(a3, off, 64);
            a4 += __shfl_xor(a4, off, 64); a5 += __shfl_xor(a5, off, 64);
            a6 += __shfl_xor(a6, off, 64); a7 += __shfl_xor(a7, off, 64);
        }
        int v = bin * BKEYS + lv;
        if (slot == 0 && v < N) {
            float nv = rsqrtf(fmaxf((float)dg, 1.0f));
            const float* bq = bsh + q * 8;
            float4 o0, o1;
            o0.x = fmaxf(a0 * nv + bq[0], 0.f);
            o0.y = fmaxf(a1 * nv + bq[1], 0.f);
            o0.z = fmaxf(a2 * nv + bq[2], 0.f);
            o0.w = fmaxf(a3 * nv + bq[3], 0.f);
            o1.x = fmaxf(a4 * nv + bq[4], 0.f);
            o1.y = fmaxf(a5 * nv + bq[5], 0.f);
            o1.z = fmaxf(a6 * nv + bq[6], 0.f);
            o1.w = fmaxf(a7 * nv + bq[7], 0.f);
            float* op = out + (size_t)v * HID + q * 8;
            *(float4*)op = o0;
            *(float4*)(op + 4) = o1;
        }
    }
}

extern "C" void kernel_launch(void* const* d_in, const int* in_sizes, int n_in,
                              void* d_out, int out_size, void* d_ws, size_t ws_size,
                              hipStream_t stream) {
    const float* X   = (const float*)d_in[0];
    const int*   src = (const int*)d_in[1];
    const int*   dst = (const int*)d_in[2];
    const float* W   = (const float*)d_in[3];
    const float* b   = (const float*)d_in[4];
    float* out = (float*)d_out;

    int N = in_sizes[0] / IN_DIM;        // 100000
    int E = in_sizes[1];                 // 1600000
    int NB = (N + BKEYS - 1) / BKEYS;    // 391

    // ws (u32): [gcur_d 512][gcur_s 512][bkt_pairs NB*CAP][bkt_srcs NB*CAP][h16 N*32 halves]
    unsigned* gcur_d = (unsigned*)d_ws;
    unsigned* gcur_s = gcur_d + 512;
    unsigned* bkt_pairs = gcur_s + 512;
    unsigned* bkt_srcs  = bkt_pairs + (size_t)NB * CAP;
    unsigned short* h16 = (unsigned short*)(bkt_srcs + (size_t)NB * CAP);

    hipMemsetAsync(gcur_d, 0, 1024 * sizeof(unsigned), stream);

    multisplit_kernel<<<(E + CHUNK - 1) / CHUNK, 256, 0, stream>>>(
        src, dst, E, NB, gcur_d, gcur_s, bkt_pairs, bkt_srcs);
    degxw_kernel<<<NB, 512, 0, stream>>>(bkt_srcs, gcur_s, X, W, N, h16);
    csrgather_kernel<<<NB, 512, 0, stream>>>(bkt_pairs, gcur_d, h16, b, out, N);
}

// Round 7
// 164.320 us; speedup vs baseline: 3.0178x; 1.0817x over previous
//
#include <hip/hip_runtime.h>
#include <hip/hip_fp16.h>

#define IN_DIM 64
#define HID 32
#define SHIFT 8
#define BKEYS 256            // nodes per bin
#define CAP 4608             // bin capacity (mean 4096, sigma ~64 -> +8 sigma)
#define HCAP 2560            // half-bin CSR capacity (mean 2048, sigma ~45)
#define CHUNK 8192           // edges per multisplit block
#define MAXB 512             // max bins (N <= 131072)

// ---- K1: multisplit, direct scatter (no staging, no scan) ----
__global__ __launch_bounds__(512) void multisplit_kernel(
    const int* __restrict__ src, const int* __restrict__ dst, int E, int NB,
    unsigned* __restrict__ gcur_d, unsigned* __restrict__ gcur_s,
    unsigned* __restrict__ bkt_pairs, unsigned* __restrict__ bkt_srcs)
{
    __shared__ unsigned hist_d[MAXB], cur_d[MAXB], gb_d[MAXB];
    __shared__ unsigned hist_s[MAXB], cur_s[MAXB], gb_s[MAXB];
    int t = threadIdx.x;
    int e0 = blockIdx.x * CHUNK;
    int cnt = min(CHUNK, E - e0);
    hist_d[t] = 0; hist_s[t] = 0; cur_d[t] = 0; cur_s[t] = 0;
    __syncthreads();
    const int4* s4 = (const int4*)(src + e0);
    const int4* d4 = (const int4*)(dst + e0);
    int n4 = cnt >> 2;
    // phase 1: histogram (int4 streaming loads)
    for (int i = t; i < n4; i += 512) {
        int4 d = d4[i]; int4 s = s4[i];
        atomicAdd(&hist_d[d.x >> SHIFT], 1u); atomicAdd(&hist_s[s.x >> SHIFT], 1u);
        atomicAdd(&hist_d[d.y >> SHIFT], 1u); atomicAdd(&hist_s[s.y >> SHIFT], 1u);
        atomicAdd(&hist_d[d.z >> SHIFT], 1u); atomicAdd(&hist_s[s.z >> SHIFT], 1u);
        atomicAdd(&hist_d[d.w >> SHIFT], 1u); atomicAdd(&hist_s[s.w >> SHIFT], 1u);
    }
    for (int i = (n4 << 2) + t; i < cnt; i += 512) {
        atomicAdd(&hist_d[dst[e0 + i] >> SHIFT], 1u);
        atomicAdd(&hist_s[src[e0 + i] >> SHIFT], 1u);
    }
    __syncthreads();
    // phase 2: global range reservation
    if (t < NB) {
        unsigned hd = hist_d[t], hs = hist_s[t];
        if (hd) gb_d[t] = atomicAdd(&gcur_d[t], hd);
        if (hs) gb_s[t] = atomicAdd(&gcur_s[t], hs);
    }
    __syncthreads();
    // phase 3: rank in LDS, scatter directly to global (runs ~21 edges/bin)
    for (int i = t; i < n4; i += 512) {
        int4 d = d4[i]; int4 s = s4[i];
        int dv[4] = {d.x, d.y, d.z, d.w};
        int sv[4] = {s.x, s.y, s.z, s.w};
#pragma unroll
        for (int j = 0; j < 4; ++j) {
            int kd = dv[j] >> SHIFT;
            unsigned pos = gb_d[kd] + atomicAdd(&cur_d[kd], 1u);
            if (pos < CAP)
                bkt_pairs[(size_t)kd * CAP + pos] =
                    (((unsigned)dv[j] & (BKEYS - 1)) << 17) | (unsigned)sv[j];
            int ks = sv[j] >> SHIFT;
            unsigned pos2 = gb_s[ks] + atomicAdd(&cur_s[ks], 1u);
            if (pos2 < CAP) bkt_srcs[(size_t)ks * CAP + pos2] = (unsigned)sv[j];
        }
    }
    for (int i = (n4 << 2) + t; i < cnt; i += 512) {
        int dv = dst[e0 + i], sv = src[e0 + i];
        int kd = dv >> SHIFT;
        unsigned pos = gb_d[kd] + atomicAdd(&cur_d[kd], 1u);
        if (pos < CAP)
            bkt_pairs[(size_t)kd * CAP + pos] =
                (((unsigned)dv & (BKEYS - 1)) << 17) | (unsigned)sv;
        int ks = sv >> SHIFT;
        unsigned pos2 = gb_s[ks] + atomicAdd(&cur_s[ks], 1u);
        if (pos2 < CAP) bkt_srcs[(size_t)ks * CAP + pos2] = (unsigned)sv;
    }
}

// ---- K2: half-bin fused out-degree -> norm -> h16 = fp16((X@W)*norm) ----
__global__ __launch_bounds__(256) void degxw_kernel(
    const unsigned* __restrict__ bkt_srcs, const unsigned* __restrict__ gcur_s,
    const float* __restrict__ X, const float* __restrict__ W,
    int N, unsigned short* __restrict__ h16)
{
    __shared__ float Ws[IN_DIM * HID];   // 8 KB
    __shared__ unsigned cnt[128];
    __shared__ float nrm[128];
    int t = threadIdx.x;
    int blk = blockIdx.x, bin = blk >> 1;
    unsigned half = blk & 1;
    ((float4*)Ws)[t]       = ((const float4*)W)[t];
    ((float4*)Ws)[t + 256] = ((const float4*)W)[t + 256];
    if (t < 128) cnt[t] = 0;
    __syncthreads();
    unsigned m = gcur_s[bin];
    if (m > CAP) m = CAP;
    const unsigned* bs = bkt_srcs + (size_t)bin * CAP;
    for (unsigned i = t; i < m; i += 256) {
        unsigned k = bs[i] & (BKEYS - 1);
        if ((k >> 7) == half) atomicAdd(&cnt[k & 127], 1u);
    }
    __syncthreads();
    if (t < 128) nrm[t] = rsqrtf(fmaxf((float)cnt[t], 1.0f));
    __syncthreads();
    int q = t & 7, ln = t >> 3;          // 8 threads/node, 32 nodes/pass
#pragma unroll
    for (int pass = 0; pass < 4; ++pass) {
        int lv = pass * 32 + ln;
        int v = bin * BKEYS + (int)half * 128 + lv;
        if (v < N) {
            const float4* Xr = (const float4*)(X + (size_t)v * IN_DIM);
            float4 acc = make_float4(0.f, 0.f, 0.f, 0.f);
#pragma unroll
            for (int kk = 0; kk < 16; ++kk) {
                float4 xv = Xr[kk];
                int k0 = kk * 4;
                float4 w0 = ((float4*)Ws)[(k0 + 0) * 8 + q];
                float4 w1 = ((float4*)Ws)[(k0 + 1) * 8 + q];
                float4 w2 = ((float4*)Ws)[(k0 + 2) * 8 + q];
                float4 w3 = ((float4*)Ws)[(k0 + 3) * 8 + q];
                acc.x += xv.x * w0.x + xv.y * w1.x + xv.z * w2.x + xv.w * w3.x;
                acc.y += xv.x * w0.y + xv.y * w1.y + xv.z * w2.y + xv.w * w3.y;
                acc.z += xv.x * w0.z + xv.y * w1.z + xv.z * w2.z + xv.w * w3.z;
                acc.w += xv.x * w0.w + xv.y * w1.w + xv.z * w2.w + xv.w * w3.w;
            }
            float s = nrm[lv];
            __half2 a  = __floats2half2_rn(acc.x * s, acc.y * s);
            __half2 b2 = __floats2half2_rn(acc.z * s, acc.w * s);
            uint2 u;
            u.x = *(unsigned*)&a;
            u.y = *(unsigned*)&b2;
            ((uint2*)h16)[(size_t)v * 8 + q] = u;
        }
    }
}

// ---- K3: half-bin LDS CSR build + pull gather + fused epilogue ----
__global__ __launch_bounds__(256) void csrgather_kernel(
    const unsigned* __restrict__ bkt_pairs, const unsigned* __restrict__ gcur_d,
    const unsigned short* __restrict__ h16, const float* __restrict__ bias,
    float* __restrict__ out, int N)
{
    __shared__ unsigned cnt[128], ex[128], cur[128];
    __shared__ unsigned ecsr[HCAP];      // 10 KB
    __shared__ float bsh[HID];
    int t = threadIdx.x;
    int blk = blockIdx.x, bin = blk >> 1;
    unsigned half = blk & 1;
    if (t < 128) { cnt[t] = 0; cur[t] = 0; }
    if (t < HID) bsh[t] = bias[t];
    __syncthreads();
    unsigned m = gcur_d[bin];
    if (m > CAP) m = CAP;
    const unsigned* bp = bkt_pairs + (size_t)bin * CAP;
    for (unsigned i = t; i < m; i += 256) {
        unsigned k = bp[i] >> 17;
        if ((k >> 7) == half) atomicAdd(&cnt[k & 127], 1u);
    }
    __syncthreads();
    if (t < 128) ex[t] = cnt[t];
    __syncthreads();
    for (int off = 1; off < 128; off <<= 1) {
        unsigned u = (t >= off && t < 128) ? ex[t - off] : 0;
        __syncthreads();
        if (t < 128) ex[t] += u;         // inclusive
        __syncthreads();
    }
    for (unsigned i = t; i < m; i += 256) {
        unsigned p = bp[i];
        unsigned k = p >> 17;
        if ((k >> 7) == half) {
            unsigned kk = k & 127;
            unsigned pos = (ex[kk] - cnt[kk]) + atomicAdd(&cur[kk], 1u);
            if (pos < HCAP) ecsr[pos] = p & 0x1FFFFu;
        }
    }
    __syncthreads();
    // gather: 4 waves; per wave-iter 2 nodes x 8 edge-slots x 4 dim-quads (16B fp16)
    int lane = t & 63, w = t >> 6;
    int hsel = lane >> 5, slot = (lane >> 2) & 7, q = lane & 3;
    for (int j = 0; j < 16; ++j) {
        int lv = w * 32 + j * 2 + hsel;  // 0..127
        unsigned dg = cnt[lv];
        unsigned st = ex[lv] - dg;
        unsigned en = st + dg; if (en > HCAP) en = HCAP;
        float a0=0.f,a1=0.f,a2=0.f,a3=0.f,a4=0.f,a5=0.f,a6=0.f,a7=0.f;
        for (unsigned u = st + slot; u < en; u += 8) {
            unsigned s = ecsr[u];
            uint4 hv = ((const uint4*)h16)[(size_t)s * 4 + q];
            __half2* hp = (__half2*)&hv;
            float2 f0 = __half22float2(hp[0]);
            float2 f1 = __half22float2(hp[1]);
            float2 f2 = __half22float2(hp[2]);
            float2 f3 = __half22float2(hp[3]);
            a0 += f0.x; a1 += f0.y; a2 += f1.x; a3 += f1.y;
            a4 += f2.x; a5 += f2.y; a6 += f3.x; a7 += f3.y;
        }
#pragma unroll
        for (int off = 4; off <= 16; off <<= 1) {
            a0 += __shfl_xor(a0, off, 64); a1 += __shfl_xor(a1, off, 64);
            a2 += __shfl_xor(a2, off, 64); a3 += __shfl_xor(a3, off, 64);
            a4 += __shfl_xor(a4, off, 64); a5 += __shfl_xor(a5, off, 64);
            a6 += __shfl_xor(a6, off, 64); a7 += __shfl_xor(a7, off, 64);
        }
        int v = bin * BKEYS + (int)half * 128 + lv;
        if (slot == 0 && v < N) {
            float nv = rsqrtf(fmaxf((float)dg, 1.0f));
            const float* bq = bsh + q * 8;
            float4 o0, o1;
            o0.x = fmaxf(a0 * nv + bq[0], 0.f);
            o0.y = fmaxf(a1 * nv + bq[1], 0.f);
            o0.z = fmaxf(a2 * nv + bq[2], 0.f);
            o0.w = fmaxf(a3 * nv + bq[3], 0.f);
            o1.x = fmaxf(a4 * nv + bq[4], 0.f);
            o1.y = fmaxf(a5 * nv + bq[5], 0.f);
            o1.z = fmaxf(a6 * nv + bq[6], 0.f);
            o1.w = fmaxf(a7 * nv + bq[7], 0.f);
            float* op = out + (size_t)v * HID + q * 8;
            *(float4*)op = o0;
            *(float4*)(op + 4) = o1;
        }
    }
}

extern "C" void kernel_launch(void* const* d_in, const int* in_sizes, int n_in,
                              void* d_out, int out_size, void* d_ws, size_t ws_size,
                              hipStream_t stream) {
    const float* X   = (const float*)d_in[0];
    const int*   src = (const int*)d_in[1];
    const int*   dst = (const int*)d_in[2];
    const float* W   = (const float*)d_in[3];
    const float* b   = (const float*)d_in[4];
    float* out = (float*)d_out;

    int N = in_sizes[0] / IN_DIM;        // 100000
    int E = in_sizes[1];                 // 1600000
    int NB = (N + BKEYS - 1) / BKEYS;    // 391

    // ws (u32): [gcur_d 512][gcur_s 512][bkt_pairs NB*CAP][bkt_srcs NB*CAP][h16 N*32 halves]
    unsigned* gcur_d = (unsigned*)d_ws;
    unsigned* gcur_s = gcur_d + MAXB;
    unsigned* bkt_pairs = gcur_s + MAXB;
    unsigned* bkt_srcs  = bkt_pairs + (size_t)NB * CAP;
    unsigned short* h16 = (unsigned short*)(bkt_srcs + (size_t)NB * CAP);

    hipMemsetAsync(gcur_d, 0, 2 * MAXB * sizeof(unsigned), stream);

    multisplit_kernel<<<(E + CHUNK - 1) / CHUNK, 512, 0, stream>>>(
        src, dst, E, NB, gcur_d, gcur_s, bkt_pairs, bkt_srcs);
    degxw_kernel<<<NB * 2, 256, 0, stream>>>(bkt_srcs, gcur_s, X, W, N, h16);
    csrgather_kernel<<<NB * 2, 256, 0, stream>>>(bkt_pairs, gcur_d, h16, b, out, N);
}

// Round 8
// 149.631 us; speedup vs baseline: 3.3140x; 1.0982x over previous
//
#include <hip/hip_runtime.h>
#include <hip/hip_fp16.h>

#define IN_DIM 64
#define HID 32
#define SHIFT 8
#define BKEYS 256            // nodes per bin
#define CAP 4608             // bin capacity (mean 4096, sigma ~64 -> +8 sigma)
#define HCAP 2560            // half-bin CSR capacity (mean 2048, sigma ~45)
#define CHUNK 8192           // edges per multisplit block
#define MAXB 512             // max bins (N <= 131072)

// ---- K0: zero the reservation counters (replaces pathological fill dispatch) ----
__global__ void zero_kernel(unsigned* __restrict__ p) {
    p[threadIdx.x + blockIdx.x * 256] = 0u;   // grid 4 x 256 = 1024 words
}

// ---- K1: multisplit, direct scatter (no staging, no scan) ----
__global__ __launch_bounds__(512) void multisplit_kernel(
    const int* __restrict__ src, const int* __restrict__ dst, int E, int NB,
    unsigned* __restrict__ gcur_d, unsigned* __restrict__ gcur_s,
    unsigned* __restrict__ bkt_pairs, unsigned char* __restrict__ bkt_srcs)
{
    __shared__ unsigned hist_d[MAXB], cur_d[MAXB], gb_d[MAXB];
    __shared__ unsigned hist_s[MAXB], cur_s[MAXB], gb_s[MAXB];
    int t = threadIdx.x;
    int e0 = blockIdx.x * CHUNK;
    int cnt = min(CHUNK, E - e0);
    hist_d[t] = 0; hist_s[t] = 0; cur_d[t] = 0; cur_s[t] = 0;
    __syncthreads();
    const int4* s4 = (const int4*)(src + e0);
    const int4* d4 = (const int4*)(dst + e0);
    int n4 = cnt >> 2;
    for (int i = t; i < n4; i += 512) {
        int4 d = d4[i]; int4 s = s4[i];
        atomicAdd(&hist_d[d.x >> SHIFT], 1u); atomicAdd(&hist_s[s.x >> SHIFT], 1u);
        atomicAdd(&hist_d[d.y >> SHIFT], 1u); atomicAdd(&hist_s[s.y >> SHIFT], 1u);
        atomicAdd(&hist_d[d.z >> SHIFT], 1u); atomicAdd(&hist_s[s.z >> SHIFT], 1u);
        atomicAdd(&hist_d[d.w >> SHIFT], 1u); atomicAdd(&hist_s[s.w >> SHIFT], 1u);
    }
    for (int i = (n4 << 2) + t; i < cnt; i += 512) {
        atomicAdd(&hist_d[dst[e0 + i] >> SHIFT], 1u);
        atomicAdd(&hist_s[src[e0 + i] >> SHIFT], 1u);
    }
    __syncthreads();
    if (t < NB) {
        unsigned hd = hist_d[t], hs = hist_s[t];
        if (hd) gb_d[t] = atomicAdd(&gcur_d[t], hd);
        if (hs) gb_s[t] = atomicAdd(&gcur_s[t], hs);
    }
    __syncthreads();
    for (int i = t; i < n4; i += 512) {
        int4 d = d4[i]; int4 s = s4[i];
        int dv[4] = {d.x, d.y, d.z, d.w};
        int sv[4] = {s.x, s.y, s.z, s.w};
#pragma unroll
        for (int j = 0; j < 4; ++j) {
            int kd = dv[j] >> SHIFT;
            unsigned pos = gb_d[kd] + atomicAdd(&cur_d[kd], 1u);
            if (pos < CAP)
                bkt_pairs[(size_t)kd * CAP + pos] =
                    (((unsigned)dv[j] & (BKEYS - 1)) << 17) | (unsigned)sv[j];
            int ks = sv[j] >> SHIFT;
            unsigned pos2 = gb_s[ks] + atomicAdd(&cur_s[ks], 1u);
            if (pos2 < CAP)
                bkt_srcs[(size_t)ks * CAP + pos2] = (unsigned char)(sv[j] & (BKEYS - 1));
        }
    }
    for (int i = (n4 << 2) + t; i < cnt; i += 512) {
        int dv = dst[e0 + i], sv = src[e0 + i];
        int kd = dv >> SHIFT;
        unsigned pos = gb_d[kd] + atomicAdd(&cur_d[kd], 1u);
        if (pos < CAP)
            bkt_pairs[(size_t)kd * CAP + pos] =
                (((unsigned)dv & (BKEYS - 1)) << 17) | (unsigned)sv;
        int ks = sv >> SHIFT;
        unsigned pos2 = gb_s[ks] + atomicAdd(&cur_s[ks], 1u);
        if (pos2 < CAP)
            bkt_srcs[(size_t)ks * CAP + pos2] = (unsigned char)(sv & (BKEYS - 1));
    }
}

// ---- K2: half-bin fused out-degree -> norm -> h16 = fp16((X@W)*norm) ----
__global__ __launch_bounds__(512) void degxw_kernel(
    const unsigned char* __restrict__ bkt_srcs, const unsigned* __restrict__ gcur_s,
    const float* __restrict__ X, const float* __restrict__ W,
    int N, unsigned short* __restrict__ h16)
{
    __shared__ float Ws[IN_DIM * HID];   // 8 KB
    __shared__ unsigned cnt[128];
    __shared__ float nrm[128];
    int t = threadIdx.x;
    int blk = blockIdx.x, bin = blk >> 1;
    unsigned half = blk & 1;
    ((float4*)Ws)[t] = ((const float4*)W)[t];     // 512 float4 by 512 threads
    if (t < 128) cnt[t] = 0;
    __syncthreads();
    unsigned m = gcur_s[bin];
    if (m > CAP) m = CAP;
    const unsigned char* bs = bkt_srcs + (size_t)bin * CAP;
    const uchar4* bs4 = (const uchar4*)bs;
    unsigned m4 = m >> 2;
    for (unsigned i = t; i < m4; i += 512) {
        uchar4 kk = bs4[i];
        if ((kk.x >> 7) == half) atomicAdd(&cnt[kk.x & 127], 1u);
        if ((kk.y >> 7) == half) atomicAdd(&cnt[kk.y & 127], 1u);
        if ((kk.z >> 7) == half) atomicAdd(&cnt[kk.z & 127], 1u);
        if ((kk.w >> 7) == half) atomicAdd(&cnt[kk.w & 127], 1u);
    }
    for (unsigned i = (m4 << 2) + t; i < m; i += 512) {
        unsigned k = bs[i];
        if ((k >> 7) == half) atomicAdd(&cnt[k & 127], 1u);
    }
    __syncthreads();
    if (t < 128) nrm[t] = rsqrtf(fmaxf((float)cnt[t], 1.0f));
    __syncthreads();
    int q = t & 7, ln = t >> 3;          // 8 threads/node, 64 nodes/pass
#pragma unroll
    for (int pass = 0; pass < 2; ++pass) {
        int lv = pass * 64 + ln;
        int v = bin * BKEYS + (int)half * 128 + lv;
        if (v < N) {
            const float4* Xr = (const float4*)(X + (size_t)v * IN_DIM);
            float4 acc = make_float4(0.f, 0.f, 0.f, 0.f);
#pragma unroll
            for (int kk = 0; kk < 16; ++kk) {
                float4 xv = Xr[kk];
                int k0 = kk * 4;
                float4 w0 = ((float4*)Ws)[(k0 + 0) * 8 + q];
                float4 w1 = ((float4*)Ws)[(k0 + 1) * 8 + q];
                float4 w2 = ((float4*)Ws)[(k0 + 2) * 8 + q];
                float4 w3 = ((float4*)Ws)[(k0 + 3) * 8 + q];
                acc.x += xv.x * w0.x + xv.y * w1.x + xv.z * w2.x + xv.w * w3.x;
                acc.y += xv.x * w0.y + xv.y * w1.y + xv.z * w2.y + xv.w * w3.y;
                acc.z += xv.x * w0.z + xv.y * w1.z + xv.z * w2.z + xv.w * w3.z;
                acc.w += xv.x * w0.w + xv.y * w1.w + xv.z * w2.w + xv.w * w3.w;
            }
            float s = nrm[lv];
            __half2 a  = __floats2half2_rn(acc.x * s, acc.y * s);
            __half2 b2 = __floats2half2_rn(acc.z * s, acc.w * s);
            uint2 u;
            u.x = *(unsigned*)&a;
            u.y = *(unsigned*)&b2;
            ((uint2*)h16)[(size_t)v * 8 + q] = u;
        }
    }
}

// ---- K3: half-bin LDS CSR build + pull gather + fused epilogue (512 thr, 8 waves) ----
__global__ __launch_bounds__(512) void csrgather_kernel(
    const unsigned* __restrict__ bkt_pairs, const unsigned* __restrict__ gcur_d,
    const unsigned short* __restrict__ h16, const float* __restrict__ bias,
    float* __restrict__ out, int N)
{
    __shared__ unsigned cnt[128], ex[128], cur[128];
    __shared__ unsigned ecsr[HCAP];      // 10 KB
    __shared__ float bsh[HID];
    int t = threadIdx.x;
    int blk = blockIdx.x, bin = blk >> 1;
    unsigned half = blk & 1;
    if (t < 128) { cnt[t] = 0; cur[t] = 0; }
    if (t >= 128 && t < 128 + HID) bsh[t - 128] = bias[t - 128];
    __syncthreads();
    unsigned m = gcur_d[bin];
    if (m > CAP) m = CAP;
    const unsigned* bp = bkt_pairs + (size_t)bin * CAP;
    for (unsigned i = t; i < m; i += 512) {
        unsigned k = bp[i] >> 17;
        if ((k >> 7) == half) atomicAdd(&cnt[k & 127], 1u);
    }
    __syncthreads();
    if (t < 128) ex[t] = cnt[t];
    __syncthreads();
    for (int off = 1; off < 128; off <<= 1) {
        unsigned u = (t >= off && t < 128) ? ex[t - off] : 0;
        __syncthreads();
        if (t < 128) ex[t] += u;         // inclusive
        __syncthreads();
    }
    for (unsigned i = t; i < m; i += 512) {
        unsigned p = bp[i];
        unsigned k = p >> 17;
        if ((k >> 7) == half) {
            unsigned kk = k & 127;
            unsigned pos = (ex[kk] - cnt[kk]) + atomicAdd(&cur[kk], 1u);
            if (pos < HCAP) ecsr[pos] = p & 0x1FFFFu;
        }
    }
    __syncthreads();
    // gather: 8 waves x 16 keys each; per j-iter 2 nodes x 8 edge-slots x 4 dim-quads
    int lane = t & 63, w = t >> 6;
    int hsel = lane >> 5, slot = (lane >> 2) & 7, q = lane & 3;
    for (int j = 0; j < 8; ++j) {
        int lv = w * 16 + j * 2 + hsel;  // 0..127
        unsigned dg = cnt[lv];
        unsigned st = ex[lv] - dg;
        unsigned en = st + dg; if (en > HCAP) en = HCAP;
        float a0=0.f,a1=0.f,a2=0.f,a3=0.f,a4=0.f,a5=0.f,a6=0.f,a7=0.f;
        unsigned u = st + slot;
        for (; u + 8 < en; u += 16) {    // two independent 16B loads in flight
            unsigned s0 = ecsr[u];
            unsigned s1 = ecsr[u + 8];
            uint4 hv0 = ((const uint4*)h16)[(size_t)s0 * 4 + q];
            uint4 hv1 = ((const uint4*)h16)[(size_t)s1 * 4 + q];
            __half2* hp0 = (__half2*)&hv0;
            __half2* hp1 = (__half2*)&hv1;
            float2 f0 = __half22float2(hp0[0]), g0 = __half22float2(hp1[0]);
            float2 f1 = __half22float2(hp0[1]), g1 = __half22float2(hp1[1]);
            float2 f2 = __half22float2(hp0[2]), g2 = __half22float2(hp1[2]);
            float2 f3 = __half22float2(hp0[3]), g3 = __half22float2(hp1[3]);
            a0 += f0.x + g0.x; a1 += f0.y + g0.y;
            a2 += f1.x + g1.x; a3 += f1.y + g1.y;
            a4 += f2.x + g2.x; a5 += f2.y + g2.y;
            a6 += f3.x + g3.x; a7 += f3.y + g3.y;
        }
        if (u < en) {
            unsigned s = ecsr[u];
            uint4 hv = ((const uint4*)h16)[(size_t)s * 4 + q];
            __half2* hp = (__half2*)&hv;
            float2 f0 = __half22float2(hp[0]);
            float2 f1 = __half22float2(hp[1]);
            float2 f2 = __half22float2(hp[2]);
            float2 f3 = __half22float2(hp[3]);
            a0 += f0.x; a1 += f0.y; a2 += f1.x; a3 += f1.y;
            a4 += f2.x; a5 += f2.y; a6 += f3.x; a7 += f3.y;
        }
#pragma unroll
        for (int off = 4; off <= 16; off <<= 1) {
            a0 += __shfl_xor(a0, off, 64); a1 += __shfl_xor(a1, off, 64);
            a2 += __shfl_xor(a2, off, 64); a3 += __shfl_xor(a3, off, 64);
            a4 += __shfl_xor(a4, off, 64); a5 += __shfl_xor(a5, off, 64);
            a6 += __shfl_xor(a6, off, 64); a7 += __shfl_xor(a7, off, 64);
        }
        int v = bin * BKEYS + (int)half * 128 + lv;
        if (slot == 0 && v < N) {
            float nv = rsqrtf(fmaxf((float)dg, 1.0f));
            const float* bq = bsh + q * 8;
            float4 o0, o1;
            o0.x = fmaxf(a0 * nv + bq[0], 0.f);
            o0.y = fmaxf(a1 * nv + bq[1], 0.f);
            o0.z = fmaxf(a2 * nv + bq[2], 0.f);
            o0.w = fmaxf(a3 * nv + bq[3], 0.f);
            o1.x = fmaxf(a4 * nv + bq[4], 0.f);
            o1.y = fmaxf(a5 * nv + bq[5], 0.f);
            o1.z = fmaxf(a6 * nv + bq[6], 0.f);
            o1.w = fmaxf(a7 * nv + bq[7], 0.f);
            float* op = out + (size_t)v * HID + q * 8;
            *(float4*)op = o0;
            *(float4*)(op + 4) = o1;
        }
    }
}

extern "C" void kernel_launch(void* const* d_in, const int* in_sizes, int n_in,
                              void* d_out, int out_size, void* d_ws, size_t ws_size,
                              hipStream_t stream) {
    const float* X   = (const float*)d_in[0];
    const int*   src = (const int*)d_in[1];
    const int*   dst = (const int*)d_in[2];
    const float* W   = (const float*)d_in[3];
    const float* b   = (const float*)d_in[4];
    float* out = (float*)d_out;

    int N = in_sizes[0] / IN_DIM;        // 100000
    int E = in_sizes[1];                 // 1600000
    int NB = (N + BKEYS - 1) / BKEYS;    // 391

    // ws: [gcur_d 512 u32][gcur_s 512 u32][bkt_pairs NB*CAP u32]
    //     [bkt_srcs NB*CAP u8][h16 N*32 halves]
    unsigned* gcur_d = (unsigned*)d_ws;
    unsigned* gcur_s = gcur_d + MAXB;
    unsigned* bkt_pairs = gcur_s + MAXB;
    unsigned char* bkt_srcs = (unsigned char*)(bkt_pairs + (size_t)NB * CAP);
    unsigned short* h16 = (unsigned short*)(bkt_srcs + (size_t)NB * CAP);

    zero_kernel<<<4, 256, 0, stream>>>(gcur_d);
    multisplit_kernel<<<(E + CHUNK - 1) / CHUNK, 512, 0, stream>>>(
        src, dst, E, NB, gcur_d, gcur_s, bkt_pairs, bkt_srcs);
    degxw_kernel<<<NB * 2, 512, 0, stream>>>(bkt_srcs, gcur_s, X, W, N, h16);
    csrgather_kernel<<<NB * 2, 512, 0, stream>>>(bkt_pairs, gcur_d, h16, b, out, N);
}